// Round 3
// baseline (551.846 us; speedup 1.0000x reference)
//
#include <hip/hip_runtime.h>
#include <hip/hip_fp16.h>

// HartleyConv2d: out[b,o,u,v] = (0.5/132^2) * sum_c [ X*(W+Wf) + Xf*(W-Wf) ]
// X = DHT2(pad1(x) zero-padded to 132), Xf(u,v)=X(131-u,131-v); W rank-9 separable.
// ALL I/O fp32: x [8,64,128,128], w [64,64,3,3], out [8,64,128,128].
// Intermediates Y1, X stored fp16 (error ~1e-4 abs, threshold 2.1e-2).

#define SCALE (0.5f / 17424.0f)

__device__ __forceinline__ float ldcvt(const float* p)  { return *p; }
__device__ __forceinline__ float ldcvt(const __half* p) { return __half2float(*p); }

// ---------------------------------------------------------------- tables ----
// T [132][128]: T[u][i] = cas(2*pi*u*(i+1)/132)   (x transform, pad folded in)
// Tt[128][132]: transpose of T
__global__ void build_tables(float* __restrict__ T, float* __restrict__ Tt) {
    const int u = blockIdx.x;    // 0..131
    const int i = threadIdx.x;   // 0..127
    const int m = (u * (i + 1)) % 132;
    const float step = 6.28318530717958647692f / 132.0f;
    float s, c;
    sincosf((float)m * step, &s, &c);
    const float v = c + s;
    T[u * 128 + i]  = v;
    Tt[i * 132 + u] = v;
}

// ------------------------------------------------------------------ GEMM ----
// C[z](MxN, fp16) = A[z](MxK fp32, row-major) * B[z](KxN, row-major).  K%16==0.
// 64x64 tiles, 4x4 micro-tiles.
template <typename TB>
__global__ __launch_bounds__(256) void gemm_tiled(
    const float* __restrict__ A, const TB* __restrict__ B, __half* __restrict__ C,
    int M, int N, int K, long sA, long sB, long sC)
{
    __shared__ float As[16][68];   // [k][m], padded
    __shared__ float Bs[16][68];   // [k][n], padded
    A += (long)blockIdx.z * sA;
    B += (long)blockIdx.z * sB;
    C += (long)blockIdx.z * sC;
    const int m0 = blockIdx.y * 64, n0 = blockIdx.x * 64;
    const int tid = threadIdx.x;
    const int mb = (tid >> 4) * 4, nb = (tid & 15) * 4;   // compute micro-tile
    const int lm = tid >> 2, lk = (tid & 3) * 4;          // A staging
    const int bk = tid >> 4, bn = (tid & 15) * 4;         // B staging
    float acc[4][4] = {};

    for (int k0 = 0; k0 < K; k0 += 16) {
        // stage A tile (64 x 16) transposed into As[k][m]
        float a0 = 0.f, a1 = 0.f, a2 = 0.f, a3 = 0.f;
        const int gm = m0 + lm;
        if (gm < M) {
            const float4 q = *(const float4*)(A + (size_t)gm * K + k0 + lk);
            a0 = q.x; a1 = q.y; a2 = q.z; a3 = q.w;
        }
        As[lk + 0][lm] = a0; As[lk + 1][lm] = a1;
        As[lk + 2][lm] = a2; As[lk + 3][lm] = a3;
        // stage B tile (16 x 64), per-element guarded
        {
            const TB* bp = B + (size_t)(k0 + bk) * N;
            const int gn = n0 + bn;
            Bs[bk][bn + 0] = (gn + 0 < N) ? ldcvt(bp + gn + 0) : 0.f;
            Bs[bk][bn + 1] = (gn + 1 < N) ? ldcvt(bp + gn + 1) : 0.f;
            Bs[bk][bn + 2] = (gn + 2 < N) ? ldcvt(bp + gn + 2) : 0.f;
            Bs[bk][bn + 3] = (gn + 3 < N) ? ldcvt(bp + gn + 3) : 0.f;
        }
        __syncthreads();
        #pragma unroll
        for (int k = 0; k < 16; ++k) {
            const float4 av = *(const float4*)&As[k][mb];
            const float4 bv = *(const float4*)&Bs[k][nb];
            acc[0][0] += av.x * bv.x; acc[0][1] += av.x * bv.y;
            acc[0][2] += av.x * bv.z; acc[0][3] += av.x * bv.w;
            acc[1][0] += av.y * bv.x; acc[1][1] += av.y * bv.y;
            acc[1][2] += av.y * bv.z; acc[1][3] += av.y * bv.w;
            acc[2][0] += av.z * bv.x; acc[2][1] += av.z * bv.y;
            acc[2][2] += av.z * bv.z; acc[2][3] += av.z * bv.w;
            acc[3][0] += av.w * bv.x; acc[3][1] += av.w * bv.y;
            acc[3][2] += av.w * bv.z; acc[3][3] += av.w * bv.w;
        }
        __syncthreads();
    }
    #pragma unroll
    for (int i2 = 0; i2 < 4; ++i2) {
        const int gm = m0 + mb + i2;
        if (gm < M) {
            #pragma unroll
            for (int j = 0; j < 4; ++j) {
                const int gn = n0 + nb + j;
                if (gn < N) C[(size_t)gm * N + gn] = __float2half(acc[i2][j]);
            }
        }
    }
}

// --------------------------------------------------------------- combine ----
// grid (32 vgroups, 128 u, 2 o-halves), 256 threads.
// Block: fixed u, v in [v0,v0+4), o in [o0,o0+32), all b, all c.
// thread: op = tid&15 -> o = o0+op, o0+op+16 ; cq = tid>>4 -> c = cq*4..+3
__global__ __launch_bounds__(256) void combine_kernel(
    const __half* __restrict__ X, const float* __restrict__ wf,
    float* __restrict__ out)
{
    const int v0 = blockIdx.x * 4;
    const int u  = blockIdx.y;
    const int o0 = blockIdx.z * 32;
    const int tid = threadIdx.x;

    __shared__ float PL[64][36];       // [c][vv*8+b] = X + Xf  (stride 36, bank-safe)
    __shared__ float ML[64][36];       // [c][vv*8+b] = X - Xf
    __shared__ float red[4][16][64];   // inter-wave reduction

    // ---- stage P/M
    for (int idx = tid; idx < 2048; idx += 256) {
        const int b = idx >> 8, c = (idx >> 2) & 63, vv = idx & 3;
        const size_t base = (size_t)(b * 64 + c) * 17424;   // 132*132
        const float x1 = __half2float(X[base + (size_t)u * 132 + (v0 + vv)]);
        const float x2 = __half2float(X[base + (size_t)(131 - u) * 132 + (131 - v0 - vv)]);
        PL[c][vv * 8 + b] = x1 + x2;
        ML[c][vv * 8 + b] = x1 - x2;
    }
    // ---- per-thread coefficients (weights at offset 0: phases u*i; flip: -(u+1)*i)
    const float step = 6.28318530717958647692f / 132.0f;
    float a[3], apc[3];
    a[0] = 1.f; apc[0] = 1.f;
    #pragma unroll
    for (int i2 = 1; i2 < 3; ++i2) {
        float s, c;
        sincosf((float)((u * i2) % 132) * step, &s, &c);
        a[i2] = c + s;                                  // cas(2pi*u*i/132)
        sincosf((float)(((u + 1) * i2) % 132) * step, &s, &c);
        apc[i2] = c - s;                                // cas(2pi*(131-u)*i/132)
    }
    float bv[4][3], bp[4][3];
    #pragma unroll
    for (int vv = 0; vv < 4; ++vv) {
        const int v = v0 + vv;
        bv[vv][0] = 1.f; bp[vv][0] = 1.f;
        #pragma unroll
        for (int j = 1; j < 3; ++j) {
            float s, c;
            sincosf((float)((v * j) % 132) * step, &s, &c);
            bv[vv][j] = c + s;
            sincosf((float)(((v + 1) * j) % 132) * step, &s, &c);
            bp[vv][j] = c - s;
        }
    }
    __syncthreads();

    // ---- main contraction
    const int op = tid & 15, cq = tid >> 4;
    float acc[64];   // index = oo*32 + b*4 + vv
    #pragma unroll
    for (int k = 0; k < 64; ++k) acc[k] = 0.f;

    #pragma unroll
    for (int cc = 0; cc < 4; ++cc) {
        const int c = cq * 4 + cc;
        float h[2][3], g[2][3];
        #pragma unroll
        for (int oo = 0; oo < 2; ++oo) {
            const float* wp = wf + ((size_t)(o0 + op + oo * 16) * 64 + c) * 9;
            float w9[9];
            #pragma unroll
            for (int q = 0; q < 9; ++q) w9[q] = wp[q];
            #pragma unroll
            for (int j = 0; j < 3; ++j) {
                h[oo][j] = a[0]  * w9[j] + a[1]  * w9[3 + j] + a[2]  * w9[6 + j];
                g[oo][j] = apc[0]* w9[j] + apc[1]* w9[3 + j] + apc[2]* w9[6 + j];
            }
        }
        #pragma unroll
        for (int vv = 0; vv < 4; ++vv) {
            const float4 p0 = *(const float4*)&PL[c][vv * 8];
            const float4 p1 = *(const float4*)&PL[c][vv * 8 + 4];
            const float4 q0 = *(const float4*)&ML[c][vv * 8];
            const float4 q1 = *(const float4*)&ML[c][vv * 8 + 4];
            #pragma unroll
            for (int oo = 0; oo < 2; ++oo) {
                const float t1 = h[oo][0] * bv[vv][0] + h[oo][1] * bv[vv][1] + h[oo][2] * bv[vv][2];
                const float t2 = g[oo][0] * bp[vv][0] + g[oo][1] * bp[vv][1] + g[oo][2] * bp[vv][2];
                float* ac = &acc[oo * 32 + vv];
                ac[0]  += p0.x * t1 + q0.x * t2;
                ac[4]  += p0.y * t1 + q0.y * t2;
                ac[8]  += p0.z * t1 + q0.z * t2;
                ac[12] += p0.w * t1 + q0.w * t2;
                ac[16] += p1.x * t1 + q1.x * t2;
                ac[20] += p1.y * t1 + q1.y * t2;
                ac[24] += p1.z * t1 + q1.z * t2;
                ac[28] += p1.w * t1 + q1.w * t2;
            }
        }
    }

    // ---- reduce over cq: intra-wave (xor 16, 32), then across 4 waves via LDS
    #pragma unroll
    for (int k = 0; k < 64; ++k) {
        acc[k] += __shfl_xor(acc[k], 16, 64);
        acc[k] += __shfl_xor(acc[k], 32, 64);
    }
    const int lane = tid & 63, wv = tid >> 6;
    if (lane < 16) {
        #pragma unroll
        for (int k = 0; k < 64; ++k) red[wv][lane][k] = acc[k];
    }
    __syncthreads();
    for (int s = tid; s < 1024; s += 256) {
        const int op2 = s >> 6, k = s & 63;
        float val = red[0][op2][k] + red[1][op2][k] + red[2][op2][k] + red[3][op2][k];
        val *= SCALE;
        const int oo = k >> 5, r = k & 31, b = r >> 2, vv = r & 3;
        const int o = o0 + op2 + oo * 16;
        out[((size_t)(b * 64 + o) * 128 + u) * 128 + (v0 + vv)] = val;
    }
}

// ----------------------------------------------------------------- launch ----
extern "C" void kernel_launch(void* const* d_in, const int* in_sizes, int n_in,
                              void* d_out, int out_size, void* d_ws, size_t ws_size,
                              hipStream_t stream)
{
    const float* x = (const float*)d_in[0];   // fp32 [8,64,128,128]
    const float* w = (const float*)d_in[1];   // fp32 [64,64,3,3]
    char* ws = (char*)d_ws;
    // byte layout:
    //   T  fp32 @ 0          (67,584 B)
    //   Tt fp32 @ 67,584     (67,584 B)
    //   Y1 fp16 @ 135,168    (17,301,504 B)  [65536 x 132]
    //   X  fp16 @ 17,436,672 (17,842,176 B)  [512 x 132 x 132]
    // total ~33.6 MB
    float*  T  = (float*)(ws);
    float*  Tt = (float*)(ws + 67584);
    __half* Y1 = (__half*)(ws + 135168);
    __half* X  = (__half*)(ws + 17436672);

    build_tables<<<dim3(132), dim3(128), 0, stream>>>(T, Tt);

    // pass 1: Y1[bc*128+i][v] = sum_j x[bc,i,j] * cas(2pi v (j+1)/132)
    gemm_tiled<float><<<dim3(3, 1024, 1), dim3(256), 0, stream>>>(
        x, Tt, Y1, 65536, 132, 128, 0, 0, 0);

    // pass 2 (batched over bc): X[bc][u][v] = sum_i T[u][i] * Y1[bc][i][v]
    gemm_tiled<__half><<<dim3(3, 3, 512), dim3(256), 0, stream>>>(
        T, Y1, X, 132, 132, 128, 0, 16896, 17424);

    // combine + crop + scale -> fp32 out
    combine_kernel<<<dim3(32, 128, 2), dim3(256), 0, stream>>>(
        X, w, (float*)d_out);
}

// Round 4
// 494.935 us; speedup vs baseline: 1.1150x; 1.1150x over previous
//
#include <hip/hip_runtime.h>
#include <hip/hip_fp16.h>

// HartleyConv2d: out[b,o,u,v] = (0.5/132^2) * sum_c [ X*(W+Wf) + Xf*(W-Wf) ]
// X = DHT2(pad1(x) zero-padded to 132), Xf(u,v)=X(131-u,131-v); W rank-9 separable.
// ALL I/O fp32: x [8,64,128,128], w [64,64,3,3], out [8,64,128,128].
// Intermediates Y1, X fp16.  hg[u][o][c][8] = {h0,h1,h2,g0,g1,g2,0,0} fp16,
// h_j(u,o,c) = sum_i cas(2pi*u*i/132) w[o,c,i,j], g_j = sum_i cas(-2pi*(u+1)i/132) w.

#define SCALE (0.5f / 17424.0f)

__device__ __forceinline__ float ldcvt(const float* p)  { return *p; }
__device__ __forceinline__ float ldcvt(const __half* p) { return __half2float(*p); }

// ---------------------------------------------------------------- tables ----
__global__ void build_tables(float* __restrict__ T, float* __restrict__ Tt) {
    const int u = blockIdx.x;    // 0..131
    const int i = threadIdx.x;   // 0..127
    const int m = (u * (i + 1)) % 132;
    const float step = 6.28318530717958647692f / 132.0f;
    float s, c;
    sincosf((float)m * step, &s, &c);
    const float v = c + s;
    T[u * 128 + i]  = v;
    Tt[i * 132 + u] = v;
}

// ------------------------------------------------------------- build_hg ----
// grid(128), 256 threads, 16 iters: hg[u][o][c][8] fp16
__global__ __launch_bounds__(256) void build_hg(
    const float* __restrict__ w, __half* __restrict__ hg)
{
    const int u = blockIdx.x;
    const float step = 6.28318530717958647692f / 132.0f;
    float a[3], ap[3];
    a[0] = 1.f; ap[0] = 1.f;
    #pragma unroll
    for (int i = 1; i < 3; ++i) {
        float s, c;
        sincosf((float)((u * i) % 132) * step, &s, &c);
        a[i] = c + s;                                   // cas(2pi*u*i/132)
        sincosf((float)(((u + 1) * i) % 132) * step, &s, &c);
        ap[i] = c - s;                                  // cas(-2pi*(u+1)*i/132)
    }
    for (int it = 0; it < 16; ++it) {
        const int oc = it * 256 + threadIdx.x;          // (o*64+c)
        const float* wp = w + (size_t)oc * 9;
        float w9[9];
        #pragma unroll
        for (int q = 0; q < 9; ++q) w9[q] = wp[q];
        __half out8[8];
        #pragma unroll
        for (int j = 0; j < 3; ++j) {
            out8[j]     = __float2half(a[0]*w9[j] + a[1]*w9[3+j] + a[2]*w9[6+j]);
            out8[3 + j] = __float2half(ap[0]*w9[j] + ap[1]*w9[3+j] + ap[2]*w9[6+j]);
        }
        out8[6] = __float2half(0.f); out8[7] = __float2half(0.f);
        *(float4*)(hg + ((size_t)u * 4096 + oc) * 8) = *(float4*)out8;
    }
}

// ------------------------------------------------------------------ GEMM ----
// C[z](MxN, fp16) = A[z](MxK fp32) * B[z](KxN).  64x64 tiles, 4x4 micro.
template <typename TB>
__global__ __launch_bounds__(256) void gemm_tiled(
    const float* __restrict__ A, const TB* __restrict__ B, __half* __restrict__ C,
    int M, int N, int K, long sA, long sB, long sC)
{
    __shared__ float As[16][68];
    __shared__ float Bs[16][68];
    A += (long)blockIdx.z * sA;
    B += (long)blockIdx.z * sB;
    C += (long)blockIdx.z * sC;
    const int m0 = blockIdx.y * 64, n0 = blockIdx.x * 64;
    const int tid = threadIdx.x;
    const int mb = (tid >> 4) * 4, nb = (tid & 15) * 4;
    const int lm = tid >> 2, lk = (tid & 3) * 4;
    const int bk = tid >> 4, bn = (tid & 15) * 4;
    float acc[4][4] = {};

    for (int k0 = 0; k0 < K; k0 += 16) {
        float a0 = 0.f, a1 = 0.f, a2 = 0.f, a3 = 0.f;
        const int gm = m0 + lm;
        if (gm < M) {
            const float4 q = *(const float4*)(A + (size_t)gm * K + k0 + lk);
            a0 = q.x; a1 = q.y; a2 = q.z; a3 = q.w;
        }
        As[lk + 0][lm] = a0; As[lk + 1][lm] = a1;
        As[lk + 2][lm] = a2; As[lk + 3][lm] = a3;
        {
            const TB* bp = B + (size_t)(k0 + bk) * N;
            const int gn = n0 + bn;
            Bs[bk][bn + 0] = (gn + 0 < N) ? ldcvt(bp + gn + 0) : 0.f;
            Bs[bk][bn + 1] = (gn + 1 < N) ? ldcvt(bp + gn + 1) : 0.f;
            Bs[bk][bn + 2] = (gn + 2 < N) ? ldcvt(bp + gn + 2) : 0.f;
            Bs[bk][bn + 3] = (gn + 3 < N) ? ldcvt(bp + gn + 3) : 0.f;
        }
        __syncthreads();
        #pragma unroll
        for (int k = 0; k < 16; ++k) {
            const float4 av = *(const float4*)&As[k][mb];
            const float4 bv = *(const float4*)&Bs[k][nb];
            acc[0][0] += av.x * bv.x; acc[0][1] += av.x * bv.y;
            acc[0][2] += av.x * bv.z; acc[0][3] += av.x * bv.w;
            acc[1][0] += av.y * bv.x; acc[1][1] += av.y * bv.y;
            acc[1][2] += av.y * bv.z; acc[1][3] += av.y * bv.w;
            acc[2][0] += av.z * bv.x; acc[2][1] += av.z * bv.y;
            acc[2][2] += av.z * bv.z; acc[2][3] += av.z * bv.w;
            acc[3][0] += av.w * bv.x; acc[3][1] += av.w * bv.y;
            acc[3][2] += av.w * bv.z; acc[3][3] += av.w * bv.w;
        }
        __syncthreads();
    }
    #pragma unroll
    for (int i2 = 0; i2 < 4; ++i2) {
        const int gm = m0 + mb + i2;
        if (gm < M) {
            #pragma unroll
            for (int j = 0; j < 4; ++j) {
                const int gn = n0 + nb + j;
                if (gn < N) C[(size_t)gm * N + gn] = __float2half(acc[i2][j]);
            }
        }
    }
}

// --------------------------------------------------------------- combine ----
// grid (32 vgroups, 128 u, 2 o-halves), 256 threads.
// thread: op = tid&15 -> o = o0+op, o0+op+16 ; cq = tid>>4 -> c = cq*4..+3
__global__ __launch_bounds__(256) void combine_kernel(
    const __half* __restrict__ X, const __half* __restrict__ hg,
    float* __restrict__ out)
{
    const int v0 = blockIdx.x * 4;
    const int u  = blockIdx.y;
    const int o0 = blockIdx.z * 32;
    const int tid = threadIdx.x;

    __shared__ float PL[64][36];       // [c][vv*8+b] = X + Xf  (stride 36)
    __shared__ float ML[64][36];       // [c][vv*8+b] = X - Xf
    __shared__ float red[4][16][66];   // padded 66: stride%32==2 -> conflict-free

    // ---- stage P/M
    for (int idx = tid; idx < 2048; idx += 256) {
        const int b = idx >> 8, c = (idx >> 2) & 63, vv = idx & 3;
        const size_t base = (size_t)(b * 64 + c) * 17424;
        const float x1 = __half2float(X[base + (size_t)u * 132 + (v0 + vv)]);
        const float x2 = __half2float(X[base + (size_t)(131 - u) * 132 + (131 - v0 - vv)]);
        PL[c][vv * 8 + b] = x1 + x2;
        ML[c][vv * 8 + b] = x1 - x2;
    }
    // ---- per-thread v coefficients
    const float step = 6.28318530717958647692f / 132.0f;
    float bv[4][3], bp[4][3];
    #pragma unroll
    for (int vv = 0; vv < 4; ++vv) {
        const int v = v0 + vv;
        bv[vv][0] = 1.f; bp[vv][0] = 1.f;
        #pragma unroll
        for (int j = 1; j < 3; ++j) {
            float s, c;
            sincosf((float)((v * j) % 132) * step, &s, &c);
            bv[vv][j] = c + s;
            sincosf((float)(((v + 1) * j) % 132) * step, &s, &c);
            bp[vv][j] = c - s;
        }
    }
    __syncthreads();

    // ---- main contraction
    const int op = tid & 15, cq = tid >> 4;
    const __half* hgu = hg + (size_t)u * 4096 * 8;
    float acc[64];   // index = oo*32 + b*4 + vv
    #pragma unroll
    for (int k = 0; k < 64; ++k) acc[k] = 0.f;

    #pragma unroll
    for (int cc = 0; cc < 4; ++cc) {
        const int c = cq * 4 + cc;
        // hoisted vector weight loads: hg[u][o][c][0..7]
        float4 hq[2];
        hq[0] = *(const float4*)(hgu + ((size_t)(o0 + op) * 64 + c) * 8);
        hq[1] = *(const float4*)(hgu + ((size_t)(o0 + op + 16) * 64 + c) * 8);
        float h[2][3], g[2][3];
        #pragma unroll
        for (int oo = 0; oo < 2; ++oo) {
            const __half* e = (const __half*)&hq[oo];
            h[oo][0] = __half2float(e[0]); h[oo][1] = __half2float(e[1]);
            h[oo][2] = __half2float(e[2]);
            g[oo][0] = __half2float(e[3]); g[oo][1] = __half2float(e[4]);
            g[oo][2] = __half2float(e[5]);
        }
        #pragma unroll
        for (int vv = 0; vv < 4; ++vv) {
            const float4 p0 = *(const float4*)&PL[c][vv * 8];
            const float4 p1 = *(const float4*)&PL[c][vv * 8 + 4];
            const float4 q0 = *(const float4*)&ML[c][vv * 8];
            const float4 q1 = *(const float4*)&ML[c][vv * 8 + 4];
            #pragma unroll
            for (int oo = 0; oo < 2; ++oo) {
                const float t1 = h[oo][0]*bv[vv][0] + h[oo][1]*bv[vv][1] + h[oo][2]*bv[vv][2];
                const float t2 = g[oo][0]*bp[vv][0] + g[oo][1]*bp[vv][1] + g[oo][2]*bp[vv][2];
                float* ac = &acc[oo * 32 + vv];
                ac[0]  += p0.x * t1 + q0.x * t2;
                ac[4]  += p0.y * t1 + q0.y * t2;
                ac[8]  += p0.z * t1 + q0.z * t2;
                ac[12] += p0.w * t1 + q0.w * t2;
                ac[16] += p1.x * t1 + q1.x * t2;
                ac[20] += p1.y * t1 + q1.y * t2;
                ac[24] += p1.z * t1 + q1.z * t2;
                ac[28] += p1.w * t1 + q1.w * t2;
            }
        }
    }

    // ---- reduce over cq: intra-wave (xor 16, 32), then across 4 waves
    #pragma unroll
    for (int k = 0; k < 64; ++k) {
        acc[k] += __shfl_xor(acc[k], 16, 64);
        acc[k] += __shfl_xor(acc[k], 32, 64);
    }
    const int lane = tid & 63, wv = tid >> 6;
    if (lane < 16) {
        #pragma unroll
        for (int k = 0; k < 64; ++k) red[wv][lane][k] = acc[k];
    }
    __syncthreads();
    for (int s = tid; s < 1024; s += 256) {
        const int op2 = s >> 6, k = s & 63;
        float val = red[0][op2][k] + red[1][op2][k] + red[2][op2][k] + red[3][op2][k];
        val *= SCALE;
        const int oo = k >> 5, r = k & 31, b = r >> 2, vv = r & 3;
        const int o = o0 + op2 + oo * 16;
        out[((size_t)(b * 64 + o) * 128 + u) * 128 + (v0 + vv)] = val;
    }
}

// ----------------------------------------------------------------- launch ----
extern "C" void kernel_launch(void* const* d_in, const int* in_sizes, int n_in,
                              void* d_out, int out_size, void* d_ws, size_t ws_size,
                              hipStream_t stream)
{
    const float* x = (const float*)d_in[0];   // fp32 [8,64,128,128]
    const float* w = (const float*)d_in[1];   // fp32 [64,64,3,3]
    char* ws = (char*)d_ws;
    // byte layout:
    //   T  fp32 @ 0          (67,584 B)
    //   Tt fp32 @ 67,584     (67,584 B)
    //   Y1 fp16 @ 135,168    (17,301,504 B)  [65536 x 132]   (dead after pass2)
    //   X  fp16 @ 17,436,672 (17,842,176 B)  [512 x 132 x 132]
    //   hg fp16 @ 135,168    (8,388,608 B)   [128][64][64][8]  (overlaps dead Y1)
    float*  T  = (float*)(ws);
    float*  Tt = (float*)(ws + 67584);
    __half* Y1 = (__half*)(ws + 135168);
    __half* X  = (__half*)(ws + 17436672);
    __half* hg = (__half*)(ws + 135168);      // reuses Y1 region after pass 2

    build_tables<<<dim3(132), dim3(128), 0, stream>>>(T, Tt);

    // pass 1: Y1[bc*128+i][v] = sum_j x[bc,i,j] * cas(2pi v (j+1)/132)
    gemm_tiled<float><<<dim3(3, 1024, 1), dim3(256), 0, stream>>>(
        x, Tt, Y1, 65536, 132, 128, 0, 0, 0);

    // pass 2 (batched over bc): X[bc][u][v] = sum_i T[u][i] * Y1[bc][i][v]
    gemm_tiled<__half><<<dim3(3, 3, 512), dim3(256), 0, stream>>>(
        T, Y1, X, 132, 132, 128, 0, 16896, 17424);

    // per-u weight transform (after pass2: Y1 region is dead)
    build_hg<<<dim3(128), dim3(256), 0, stream>>>(w, hg);

    // combine + crop + scale -> fp32 out
    combine_kernel<<<dim3(32, 128, 2), dim3(256), 0, stream>>>(
        X, hg, (float*)d_out);
}

// Round 5
// 233.596 us; speedup vs baseline: 2.3624x; 2.1188x over previous
//
#include <hip/hip_runtime.h>
#include <hip/hip_fp16.h>

// HartleyConv2d: out[b,o,u,v] = (0.5/132^2) * sum_c [ X*(W+Wf) + Xf*(W-Wf) ]
// X = DHT2(pad1(x) zero-padded to 132), Xf(u,v)=X(131-u,131-v); W rank-9 separable.
// ALL I/O fp32: x [8,64,128,128], w [64,64,3,3], out [8,64,128,128].
// Combine reformulated as MFMA GEMM per (u,b):
//   out[o,v] = SCALE * sum_{kt,c} hgT[u][kt][o][c] * E[kt][c][v]
//   kt = s*3+j;  E = (s==0 ? P : M)[c][v] * coef_{s,j}(v)
//   P = X(u,v)+X(131-u,131-v), M = X(u,v)-X(131-u,131-v)
//   coef_{0,j}(v) = cas(2pi v j/132), coef_{1,j}(v) = cos-sin(2pi (v+1) j/132)

#define SCALE (0.5f / 17424.0f)

typedef __attribute__((ext_vector_type(8))) _Float16 f16x8;
typedef __attribute__((ext_vector_type(4))) _Float16 f16x4;
typedef __attribute__((ext_vector_type(4))) float    f32x4;

__device__ __forceinline__ float ldcvt(const float* p)  { return *p; }
__device__ __forceinline__ float ldcvt(const __half* p) { return __half2float(*p); }

// ---------------------------------------------------------------- tables ----
__global__ void build_tables(float* __restrict__ T, float* __restrict__ Tt) {
    const int u = blockIdx.x;    // 0..131
    const int i = threadIdx.x;   // 0..127
    const int m = (u * (i + 1)) % 132;
    const float step = 6.28318530717958647692f / 132.0f;
    float s, c;
    sincosf((float)m * step, &s, &c);
    const float v = c + s;
    T[u * 128 + i]  = v;
    Tt[i * 132 + u] = v;
}

// ------------------------------------------------------------ build_hgT ----
// hgT[u][kt][o][c], kt=0..2 -> h_j, kt=3..5 -> g_j   (f16)
__global__ __launch_bounds__(256) void build_hgT(
    const float* __restrict__ w, __half* __restrict__ hgT)
{
    const int u = blockIdx.x;   // 0..127
    const float step = 6.28318530717958647692f / 132.0f;
    float a[3], ap[3];
    a[0] = 1.f; ap[0] = 1.f;
    #pragma unroll
    for (int i = 1; i < 3; ++i) {
        float s, c;
        sincosf((float)((u * i) % 132) * step, &s, &c);
        a[i] = c + s;                                   // cas(2pi*u*i/132)
        sincosf((float)(((u + 1) * i) % 132) * step, &s, &c);
        ap[i] = c - s;                                  // cas(-2pi*(u+1)*i/132)
    }
    for (int it = 0; it < 16; ++it) {
        const int oc = it * 256 + threadIdx.x;          // o*64+c
        const float* wp = w + (size_t)oc * 9;
        float w9[9];
        #pragma unroll
        for (int q = 0; q < 9; ++q) w9[q] = wp[q];
        #pragma unroll
        for (int j = 0; j < 3; ++j) {
            const float h = a[0]*w9[j] + a[1]*w9[3+j] + a[2]*w9[6+j];
            const float g = ap[0]*w9[j] + ap[1]*w9[3+j] + ap[2]*w9[6+j];
            hgT[((size_t)u * 6 + j)     * 4096 + oc] = __float2half(h);
            hgT[((size_t)u * 6 + 3 + j) * 4096 + oc] = __float2half(g);
        }
    }
}

// ------------------------------------------------------------------ GEMM ----
// C[z](MxN, fp16) = A[z](MxK fp32) * B[z](KxN).  64x64 tiles, 4x4 micro.
template <typename TB>
__global__ __launch_bounds__(256) void gemm_tiled(
    const float* __restrict__ A, const TB* __restrict__ B, __half* __restrict__ C,
    int M, int N, int K, long sA, long sB, long sC)
{
    __shared__ float As[16][68];
    __shared__ float Bs[16][68];
    A += (long)blockIdx.z * sA;
    B += (long)blockIdx.z * sB;
    C += (long)blockIdx.z * sC;
    const int m0 = blockIdx.y * 64, n0 = blockIdx.x * 64;
    const int tid = threadIdx.x;
    const int mb = (tid >> 4) * 4, nb = (tid & 15) * 4;
    const int lm = tid >> 2, lk = (tid & 3) * 4;
    const int bk = tid >> 4, bn = (tid & 15) * 4;
    float acc[4][4] = {};

    for (int k0 = 0; k0 < K; k0 += 16) {
        float a0 = 0.f, a1 = 0.f, a2 = 0.f, a3 = 0.f;
        const int gm = m0 + lm;
        if (gm < M) {
            const float4 q = *(const float4*)(A + (size_t)gm * K + k0 + lk);
            a0 = q.x; a1 = q.y; a2 = q.z; a3 = q.w;
        }
        As[lk + 0][lm] = a0; As[lk + 1][lm] = a1;
        As[lk + 2][lm] = a2; As[lk + 3][lm] = a3;
        {
            const TB* bp = B + (size_t)(k0 + bk) * N;
            const int gn = n0 + bn;
            Bs[bk][bn + 0] = (gn + 0 < N) ? ldcvt(bp + gn + 0) : 0.f;
            Bs[bk][bn + 1] = (gn + 1 < N) ? ldcvt(bp + gn + 1) : 0.f;
            Bs[bk][bn + 2] = (gn + 2 < N) ? ldcvt(bp + gn + 2) : 0.f;
            Bs[bk][bn + 3] = (gn + 3 < N) ? ldcvt(bp + gn + 3) : 0.f;
        }
        __syncthreads();
        #pragma unroll
        for (int k = 0; k < 16; ++k) {
            const float4 av = *(const float4*)&As[k][mb];
            const float4 bv = *(const float4*)&Bs[k][nb];
            acc[0][0] += av.x * bv.x; acc[0][1] += av.x * bv.y;
            acc[0][2] += av.x * bv.z; acc[0][3] += av.x * bv.w;
            acc[1][0] += av.y * bv.x; acc[1][1] += av.y * bv.y;
            acc[1][2] += av.y * bv.z; acc[1][3] += av.y * bv.w;
            acc[2][0] += av.z * bv.x; acc[2][1] += av.z * bv.y;
            acc[2][2] += av.z * bv.z; acc[2][3] += av.z * bv.w;
            acc[3][0] += av.w * bv.x; acc[3][1] += av.w * bv.y;
            acc[3][2] += av.w * bv.z; acc[3][3] += av.w * bv.w;
        }
        __syncthreads();
    }
    #pragma unroll
    for (int i2 = 0; i2 < 4; ++i2) {
        const int gm = m0 + mb + i2;
        if (gm < M) {
            #pragma unroll
            for (int j = 0; j < 4; ++j) {
                const int gn = n0 + nb + j;
                if (gn < N) C[(size_t)gm * N + gn] = __float2half(acc[i2][j]);
            }
        }
    }
}

// ---------------------------------------------------------- combine MFMA ----
// grid (128 u, 8 b), 256 threads (4 waves). Per block: M=64(o), N=128(v), K=384.
// Wave w handles v in [w*32, w*32+32).  mfma_f32_16x16x32_f16:
//   A[m=lane&15][k=quad*8+j], B[k=quad*8+j][n=lane&15], D col=lane&15 row=quad*4+reg
__global__ __launch_bounds__(256) void combine_mfma(
    const __half* __restrict__ Xh, const __half* __restrict__ hgTh,
    float* __restrict__ out)
{
    const int u = blockIdx.x;       // 0..127
    const int b = blockIdx.y;       // 0..7
    const int tid = threadIdx.x;
    const int wv = tid >> 6, lane = tid & 63;
    const int col = lane & 15, quad = lane >> 4;

    __shared__ _Float16 Ps[128][72];   // [v][c], stride 72 (bank-safe)
    __shared__ _Float16 Ms[128][72];

    const _Float16* X = (const _Float16*)Xh;

    // ---- stage P/M: thread -> c = tid>>2, vq = (tid&3)*32, 8 quads of 4 v
    {
        const int c  = tid >> 2;
        const int vq = (tid & 3) * 32;
        const _Float16* rowd = X + (size_t)(b * 64 + c) * 17424 + (size_t)u * 132;
        const _Float16* rowm = X + (size_t)(b * 64 + c) * 17424 + (size_t)(131 - u) * 132;
        #pragma unroll
        for (int k = 0; k < 8; ++k) {
            const int v0 = vq + 4 * k;
            const f16x4 d = *(const f16x4*)(rowd + v0);          // X(u, v0..v0+3)
            const f16x4 m = *(const f16x4*)(rowm + (128 - v0));  // X(131-u, 128-v0..131-v0)
            // m[i] = Xf(u, v0+3-i)
            #pragma unroll
            for (int i = 0; i < 4; ++i) {
                Ps[v0 + i][c] = d[i] + m[3 - i];
                Ms[v0 + i][c] = d[i] - m[3 - i];
            }
        }
    }

    // ---- per-lane coefficients: cf[nt][kt] for v = wv*32 + nt*16 + col
    const float step = 6.28318530717958647692f / 132.0f;
    _Float16 cf[2][6];
    #pragma unroll
    for (int nt = 0; nt < 2; ++nt) {
        const int v = wv * 32 + nt * 16 + col;
        cf[nt][0] = (_Float16)1.0f;
        cf[nt][3] = (_Float16)1.0f;
        #pragma unroll
        for (int j = 1; j < 3; ++j) {
            float s, c;
            sincosf((float)((v * j) % 132) * step, &s, &c);
            cf[nt][j] = (_Float16)(c + s);                 // bv_j(v)
            sincosf((float)(((v + 1) * j) % 132) * step, &s, &c);
            cf[nt][3 + j] = (_Float16)(c - s);             // bp_j(v)
        }
    }
    __syncthreads();

    // ---- MFMA main loop: 12 K-chunks of 32 (kt = chunk>>1, c0 = (chunk&1)*32)
    const _Float16* hgu = (const _Float16*)hgTh + (size_t)u * 6 * 4096;
    f32x4 acc[4][2];
    #pragma unroll
    for (int mt = 0; mt < 4; ++mt)
        #pragma unroll
        for (int nt = 0; nt < 2; ++nt)
            acc[mt][nt] = (f32x4)0.0f;

    #pragma unroll
    for (int ch = 0; ch < 12; ++ch) {
        const int kt = ch >> 1, c0 = (ch & 1) * 32;
        f16x8 af[4];
        #pragma unroll
        for (int mt = 0; mt < 4; ++mt) {
            const int o = mt * 16 + col;
            af[mt] = *(const f16x8*)(hgu + ((size_t)kt * 64 + o) * 64 + c0 + quad * 8);
        }
        #pragma unroll
        for (int nt = 0; nt < 2; ++nt) {
            const int v = wv * 32 + nt * 16 + col;
            f16x8 bf = (kt < 3)
                ? *(const f16x8*)&Ps[v][c0 + quad * 8]
                : *(const f16x8*)&Ms[v][c0 + quad * 8];
            const _Float16 cs = cf[nt][kt];
            #pragma unroll
            for (int e = 0; e < 8; ++e) bf[e] *= cs;
            #pragma unroll
            for (int mt = 0; mt < 4; ++mt)
                acc[mt][nt] = __builtin_amdgcn_mfma_f32_16x16x32_f16(
                    af[mt], bf, acc[mt][nt], 0, 0, 0);
        }
    }

    // ---- epilogue: C-layout -> out[b][o][u][v], coalesced 64B in v
    #pragma unroll
    for (int mt = 0; mt < 4; ++mt) {
        #pragma unroll
        for (int nt = 0; nt < 2; ++nt) {
            const int v = wv * 32 + nt * 16 + col;
            #pragma unroll
            for (int r = 0; r < 4; ++r) {
                const int o = mt * 16 + quad * 4 + r;
                out[(((size_t)b * 64 + o) * 128 + u) * 128 + v] = acc[mt][nt][r] * SCALE;
            }
        }
    }
}

// ----------------------------------------------------------------- launch ----
extern "C" void kernel_launch(void* const* d_in, const int* in_sizes, int n_in,
                              void* d_out, int out_size, void* d_ws, size_t ws_size,
                              hipStream_t stream)
{
    const float* x = (const float*)d_in[0];   // fp32 [8,64,128,128]
    const float* w = (const float*)d_in[1];   // fp32 [64,64,3,3]
    char* ws = (char*)d_ws;
    // byte layout:
    //   T   fp32 @ 0          (67,584 B)
    //   Tt  fp32 @ 67,584     (67,584 B)
    //   Y1  fp16 @ 135,168    (17,301,504 B) [65536 x 132]  (dead after pass2)
    //   X   fp16 @ 17,436,672 (17,842,176 B) [512 x 132 x 132]
    //   hgT fp16 @ 135,168    (6,291,456 B)  [128][6][64][64] (overlaps dead Y1)
    // total ~35.3 MB
    float*  T   = (float*)(ws);
    float*  Tt  = (float*)(ws + 67584);
    __half* Y1  = (__half*)(ws + 135168);
    __half* X   = (__half*)(ws + 17436672);
    __half* hgT = (__half*)(ws + 135168);     // reuses Y1 region after pass 2

    build_tables<<<dim3(132), dim3(128), 0, stream>>>(T, Tt);

    // pass 1: Y1[bc*128+i][v] = sum_j x[bc,i,j] * cas(2pi v (j+1)/132)
    gemm_tiled<float><<<dim3(3, 1024, 1), dim3(256), 0, stream>>>(
        x, Tt, Y1, 65536, 132, 128, 0, 0, 0);

    // pass 2 (batched over bc): X[bc][u][v] = sum_i T[u][i] * Y1[bc][i][v]
    gemm_tiled<__half><<<dim3(3, 3, 512), dim3(256), 0, stream>>>(
        T, Y1, X, 132, 132, 128, 0, 16896, 17424);

    // per-u weight transform (Y1 region dead after pass 2)
    build_hgT<<<dim3(128), dim3(256), 0, stream>>>(w, hgT);

    // combine as MFMA GEMM -> fp32 out
    combine_mfma<<<dim3(128, 8), dim3(256), 0, stream>>>(
        X, hgT, (float*)d_out);
}

// Round 6
// 159.197 us; speedup vs baseline: 3.4664x; 1.4673x over previous
//
#include <hip/hip_runtime.h>
#include <hip/hip_fp16.h>

// HartleyConv2d: out[b,o,u,v] = (0.5/132^2) * sum_c [ X*(W+Wf) + Xf*(W-Wf) ]
// X = DHT2(pad1(x) zero-padded to 132); both DHT passes share the same
// phase-shifted cas table T[r][k] = cas(2pi r (k+1) / 132)  (spatial pad folds in).
// ALL I/O fp32: x [8,64,128,128], w [64,64,3,3], out [8,64,128,128].
// dht2_fused: one block per (b,c) plane; Y1 kept in LDS (never hits HBM).

#define SCALE (0.5f / 17424.0f)

typedef __attribute__((ext_vector_type(8))) _Float16 f16x8;
typedef __attribute__((ext_vector_type(4))) _Float16 f16x4;
typedef __attribute__((ext_vector_type(4))) float    f32x4;

// ---------------------------------------------------------------- table ----
// Tf [144][128] f16: rows 132..143 are zero padding (for 9x16 m/n tiles).
__global__ void build_tf16(_Float16* __restrict__ Tf) {
    const int u = blockIdx.x;    // 0..143
    const int i = threadIdx.x;   // 0..127
    float val = 0.f;
    if (u < 132) {
        const int m = (u * (i + 1)) % 132;
        const float step = 6.28318530717958647692f / 132.0f;
        float s, c;
        sincosf((float)m * step, &s, &c);
        val = c + s;
    }
    Tf[u * 128 + i] = (_Float16)val;
}

// ------------------------------------------------------------ build_hgT ----
// hgT[u][kt][o][c], kt=0..2 -> h_j, kt=3..5 -> g_j   (f16)
__global__ __launch_bounds__(256) void build_hgT(
    const float* __restrict__ w, __half* __restrict__ hgT)
{
    const int u = blockIdx.x;   // 0..127
    const float step = 6.28318530717958647692f / 132.0f;
    float a[3], ap[3];
    a[0] = 1.f; ap[0] = 1.f;
    #pragma unroll
    for (int i = 1; i < 3; ++i) {
        float s, c;
        sincosf((float)((u * i) % 132) * step, &s, &c);
        a[i] = c + s;                                   // cas(2pi*u*i/132)
        sincosf((float)(((u + 1) * i) % 132) * step, &s, &c);
        ap[i] = c - s;                                  // cas(-2pi*(u+1)*i/132)
    }
    for (int it = 0; it < 16; ++it) {
        const int oc = it * 256 + threadIdx.x;          // o*64+c
        const float* wp = w + (size_t)oc * 9;
        float w9[9];
        #pragma unroll
        for (int q = 0; q < 9; ++q) w9[q] = wp[q];
        #pragma unroll
        for (int j = 0; j < 3; ++j) {
            const float h = a[0]*w9[j] + a[1]*w9[3+j] + a[2]*w9[6+j];
            const float g = ap[0]*w9[j] + ap[1]*w9[3+j] + ap[2]*w9[6+j];
            hgT[((size_t)u * 6 + j)     * 4096 + oc] = __float2half(h);
            hgT[((size_t)u * 6 + 3 + j) * 4096 + oc] = __float2half(g);
        }
    }
}

// ------------------------------------------------------------ dht2_fused ----
// grid(512): block = one (b,c) plane, 256 threads (4 waves).
// pass A: Y1l[v][i] = sum_j Tf[v][j] * x[i][j]   (v 0..143 incl. zero rows)
// pass B: X[u][v]   = sum_i Tf[u][i] * Y1l[v][i]
// mfma_f32_16x16x32_f16: arg0 rows = D rows (col-indexed), K contiguous at quad*8.
__global__ __launch_bounds__(256) void dht2_fused(
    const float* __restrict__ x, const _Float16* __restrict__ Tf,
    _Float16* __restrict__ X)
{
    const int bc = blockIdx.x;
    const int tid = threadIdx.x, wv = tid >> 6, lane = tid & 63;
    const int col = lane & 15, quad = lane >> 4;
    __shared__ _Float16 Y1l[144][136];   // [v][i], i-stride 136 (bank-safe)

    const float* xp = x + (size_t)bc * 16384;

    // ---- pass A: wave wv covers i-tiles {2wv, 2wv+1}, all 9 v-tiles
    #pragma unroll
    for (int nt = 0; nt < 2; ++nt) {
        const int ic = (wv * 2 + nt) * 16 + col;        // i of B-frag / D col
        f32x4 acc[9];
        #pragma unroll
        for (int mt = 0; mt < 9; ++mt) acc[mt] = (f32x4)0.f;
        #pragma unroll
        for (int kc = 0; kc < 4; ++kc) {
            const int k0 = kc * 32 + quad * 8;
            const float4 xa = *(const float4*)(xp + (size_t)ic * 128 + k0);
            const float4 xb = *(const float4*)(xp + (size_t)ic * 128 + k0 + 4);
            f16x8 bf;
            bf[0] = (_Float16)xa.x; bf[1] = (_Float16)xa.y;
            bf[2] = (_Float16)xa.z; bf[3] = (_Float16)xa.w;
            bf[4] = (_Float16)xb.x; bf[5] = (_Float16)xb.y;
            bf[6] = (_Float16)xb.z; bf[7] = (_Float16)xb.w;
            #pragma unroll
            for (int mt = 0; mt < 9; ++mt) {
                const f16x8 af = *(const f16x8*)(Tf + (size_t)(mt * 16 + col) * 128 + k0);
                acc[mt] = __builtin_amdgcn_mfma_f32_16x16x32_f16(af, bf, acc[mt], 0, 0, 0);
            }
        }
        #pragma unroll
        for (int mt = 0; mt < 9; ++mt)
            #pragma unroll
            for (int r = 0; r < 4; ++r)
                Y1l[mt * 16 + quad * 4 + r][ic] = (_Float16)acc[mt][r];
    }
    __syncthreads();

    // ---- pass B: wave wv covers v-tiles {wv, wv+4, wv+8}
    _Float16* Xp = X + (size_t)bc * 17424;
    #pragma unroll
    for (int c3 = 0; c3 < 3; ++c3) {
        const int nt = wv + 4 * c3;
        if (nt < 9) {
            const int vv = nt * 16 + col;               // v of B-frag / D col
            f32x4 acc[9];
            #pragma unroll
            for (int mt = 0; mt < 9; ++mt) acc[mt] = (f32x4)0.f;
            #pragma unroll
            for (int kc = 0; kc < 4; ++kc) {
                const int k0 = kc * 32 + quad * 8;
                const f16x8 bf = *(const f16x8*)&Y1l[vv][k0];
                #pragma unroll
                for (int mt = 0; mt < 9; ++mt) {
                    const f16x8 af = *(const f16x8*)(Tf + (size_t)(mt * 16 + col) * 128 + k0);
                    acc[mt] = __builtin_amdgcn_mfma_f32_16x16x32_f16(af, bf, acc[mt], 0, 0, 0);
                }
            }
            if (vv < 132) {
                #pragma unroll
                for (int mt = 0; mt < 9; ++mt) {
                    #pragma unroll
                    for (int r = 0; r < 4; ++r) {
                        const int u = mt * 16 + quad * 4 + r;
                        if (u < 132) Xp[u * 132 + vv] = (_Float16)acc[mt][r];
                    }
                }
            }
        }
    }
}

// ---------------------------------------------------------- combine MFMA ----
// grid (128 u, 8 b), 256 threads (4 waves). Per block: M=64(o), N=128(v), K=384.
__global__ __launch_bounds__(256) void combine_mfma(
    const __half* __restrict__ Xh, const __half* __restrict__ hgTh,
    float* __restrict__ out)
{
    const int u = blockIdx.x;       // 0..127
    const int b = blockIdx.y;       // 0..7
    const int tid = threadIdx.x;
    const int wv = tid >> 6, lane = tid & 63;
    const int col = lane & 15, quad = lane >> 4;

    __shared__ _Float16 Ps[128][72];   // [v][c], stride 72 (bank-safe)
    __shared__ _Float16 Ms[128][72];

    const _Float16* X = (const _Float16*)Xh;

    // ---- stage P/M: thread -> c = tid>>2, vq = (tid&3)*32, 8 quads of 4 v
    {
        const int c  = tid >> 2;
        const int vq = (tid & 3) * 32;
        const _Float16* rowd = X + (size_t)(b * 64 + c) * 17424 + (size_t)u * 132;
        const _Float16* rowm = X + (size_t)(b * 64 + c) * 17424 + (size_t)(131 - u) * 132;
        #pragma unroll
        for (int k = 0; k < 8; ++k) {
            const int v0 = vq + 4 * k;
            const f16x4 d = *(const f16x4*)(rowd + v0);          // X(u, v0..v0+3)
            const f16x4 m = *(const f16x4*)(rowm + (128 - v0));  // X(131-u, 128-v0..131-v0)
            #pragma unroll
            for (int i = 0; i < 4; ++i) {
                Ps[v0 + i][c] = d[i] + m[3 - i];
                Ms[v0 + i][c] = d[i] - m[3 - i];
            }
        }
    }

    // ---- per-lane coefficients: cf[nt][kt] for v = wv*32 + nt*16 + col
    const float step = 6.28318530717958647692f / 132.0f;
    _Float16 cf[2][6];
    #pragma unroll
    for (int nt = 0; nt < 2; ++nt) {
        const int v = wv * 32 + nt * 16 + col;
        cf[nt][0] = (_Float16)1.0f;
        cf[nt][3] = (_Float16)1.0f;
        #pragma unroll
        for (int j = 1; j < 3; ++j) {
            float s, c;
            sincosf((float)((v * j) % 132) * step, &s, &c);
            cf[nt][j] = (_Float16)(c + s);                 // bv_j(v)
            sincosf((float)(((v + 1) * j) % 132) * step, &s, &c);
            cf[nt][3 + j] = (_Float16)(c - s);             // bp_j(v)
        }
    }
    __syncthreads();

    // ---- MFMA main loop: 12 K-chunks of 32 (kt = chunk>>1, c0 = (chunk&1)*32)
    const _Float16* hgu = (const _Float16*)hgTh + (size_t)u * 6 * 4096;
    f32x4 acc[4][2];
    #pragma unroll
    for (int mt = 0; mt < 4; ++mt)
        #pragma unroll
        for (int nt = 0; nt < 2; ++nt)
            acc[mt][nt] = (f32x4)0.0f;

    #pragma unroll
    for (int ch = 0; ch < 12; ++ch) {
        const int kt = ch >> 1, c0 = (ch & 1) * 32;
        f16x8 af[4];
        #pragma unroll
        for (int mt = 0; mt < 4; ++mt) {
            const int o = mt * 16 + col;
            af[mt] = *(const f16x8*)(hgu + ((size_t)kt * 64 + o) * 64 + c0 + quad * 8);
        }
        #pragma unroll
        for (int nt = 0; nt < 2; ++nt) {
            const int v = wv * 32 + nt * 16 + col;
            f16x8 bf = (kt < 3)
                ? *(const f16x8*)&Ps[v][c0 + quad * 8]
                : *(const f16x8*)&Ms[v][c0 + quad * 8];
            const _Float16 cs = cf[nt][kt];
            #pragma unroll
            for (int e = 0; e < 8; ++e) bf[e] *= cs;
            #pragma unroll
            for (int mt = 0; mt < 4; ++mt)
                acc[mt][nt] = __builtin_amdgcn_mfma_f32_16x16x32_f16(
                    af[mt], bf, acc[mt][nt], 0, 0, 0);
        }
    }

    // ---- epilogue: C-layout -> out[b][o][u][v], coalesced 64B in v
    #pragma unroll
    for (int mt = 0; mt < 4; ++mt) {
        #pragma unroll
        for (int nt = 0; nt < 2; ++nt) {
            const int v = wv * 32 + nt * 16 + col;
            #pragma unroll
            for (int r = 0; r < 4; ++r) {
                const int o = mt * 16 + quad * 4 + r;
                out[(((size_t)b * 64 + o) * 128 + u) * 128 + v] = acc[mt][nt][r] * SCALE;
            }
        }
    }
}

// ----------------------------------------------------------------- launch ----
extern "C" void kernel_launch(void* const* d_in, const int* in_sizes, int n_in,
                              void* d_out, int out_size, void* d_ws, size_t ws_size,
                              hipStream_t stream)
{
    const float* x = (const float*)d_in[0];   // fp32 [8,64,128,128]
    const float* w = (const float*)d_in[1];   // fp32 [64,64,3,3]
    char* ws = (char*)d_ws;
    // byte layout:
    //   Tf  f16 @ 0          (36,864 B)   [144][128]
    //   X   f16 @ 65,536     (17,842,176 B) [512 x 132 x 132]
    //   hgT f16 @ 17,907,712 (6,291,456 B)  [128][6][64][64]
    // total ~24.2 MB
    _Float16* Tf  = (_Float16*)(ws);
    _Float16* X   = (_Float16*)(ws + 65536);
    __half*   hgT = (__half*)(ws + 17907712);

    build_tf16<<<dim3(144), dim3(128), 0, stream>>>(Tf);

    // fused DHT2: x -> X (Y1 stays in LDS)
    dht2_fused<<<dim3(512), dim3(256), 0, stream>>>(x, Tf, X);

    // per-u weight transform
    build_hgT<<<dim3(128), dim3(256), 0, stream>>>(w, hgT);

    // combine as MFMA GEMM -> fp32 out
    combine_mfma<<<dim3(128, 8), dim3(256), 0, stream>>>(
        (const __half*)X, hgT, (float*)d_out);
}